// Round 13
// baseline (344.894 us; speedup 1.0000x reference)
//
#include <hip/hip_runtime.h>
#include <hip/hip_cooperative_groups.h>
#include <math.h>

namespace cg = cooperative_groups;

#define BATCH 8
#define NPT   2048
#define DIM   32
#define RPB   32                      // rows per row-block: 2 strips of 16
#define CPW   (NPT / 4)               // 512 cols per wave
#define NT    (CPW / 16)              // 32 col-tiles of 16 per wave
#define L2E   1.44269504088896f
#define BN    (BATCH * NPT)

typedef __attribute__((ext_vector_type(8))) _Float16 half8;
typedef __attribute__((ext_vector_type(4))) float floatx4;
typedef unsigned short u16;
typedef unsigned int u32;

__device__ __forceinline__ u16 f2h_bits(float v) {
    _Float16 h = (_Float16)v;
    return *(u16*)&h;
}
__device__ __forceinline__ float exp2v(float x) { return __builtin_amdgcn_exp2f(x); }

// Streams: 0=F, 1=G, 2=Fx, 3=Fy. Set s reads pot-stream inS, writes stream s.
struct FusedArgs {
    const u16* A[4];       // row-side plain fp16 per set
    const u16* Bp[4];      // col-side log2e-scaled fp16 per set
    const float* qX[4];    // 0.5*||row||^2 per set
    const float* wgt[4];   // a or b per set (final dot weight)
    float sgn[4];          // +-1/BATCH
    float* pot[4][2];      // ping-pong potential buffers per stream
    float* tls[4][2];      // log2e*(pot+cw) per stream
    float* bm[4][2];       // [BATCH][128] per-16-row max of (pot+cw) per stream
    const float* cwN[4];   // cw to fold into tlsOut per set
    float* out;
};

// One damped-c-transform pass for one (set,batch,row-block).
// Factored no-rescale LSE: T = sum_k exp2(tv_k - L2E*Tmax) * exp2(log2e * x.y);
// lse = Tmax + ln(T). Dominant term >= 2^-92; wq >= 2^-101; T <= 2^103.
__device__ __forceinline__ void ct_pass(const FusedArgs& fa, int set, int batch,
                                        int rb, bool fin, int c,
                                        float lsum[RPB][4]) {
    const int tid = threadIdx.x;
    const int w = tid >> 6, lane = tid & 63, n = lane & 15, quad = lane >> 4;
    const int qk = quad * 8;
    const int row0 = rb * RPB;
    const size_t pbase = (size_t)batch * NPT * DIM;
    const size_t vbase = (size_t)batch * NPT;
    const int inS = (set == 0) ? 1 : (set == 1) ? 0 : set;

    const u16* __restrict__ Ah = fa.A[set] + pbase;
    const u16* __restrict__ Bh = fa.Bp[set] + pbase;
    const float* __restrict__ tlsIn = fa.tls[inS][c] + vbase;
    const float* __restrict__ bmIn  = fa.bm[inS][c];

    // A fragments for 2 row-strips: A[m=n][k=quad*8+j]
    half8 ah[2];
    #pragma unroll
    for (int s = 0; s < 2; s++) {
        size_t off = (size_t)(row0 + s * 16 + n) * DIM + qk;
        ah[s] = *(const half8*)(Ah + off);
    }

    // Tmax = max_k (pot_k + cw_k): wave-local reduce of 128 16-row maxes
    float tmv = fmaxf(bmIn[batch * 128 + lane], bmIn[batch * 128 + 64 + lane]);
    #pragma unroll
    for (int m = 1; m < 64; m <<= 1) tmv = fmaxf(tmv, __shfl_xor(tmv, m, 64));
    const float Tmax = tmv;
    const float l2eTmax = L2E * Tmax;

    float sum[2][4];
    #pragma unroll
    for (int s = 0; s < 2; s++)
        #pragma unroll
        for (int r = 0; r < 4; r++) sum[s][r] = 0.0f;

    const int c0 = w * CPW + n;                    // this lane's col in tile 0
    const u16* bp = Bh + (size_t)c0 * DIM + qk;    // advances 16*DIM per tile
    const float* tp = tlsIn + c0;

    half8 b0, b1;
    float t0, t1;
    b0 = *(const half8*)bp;  t0 = *tp;

    #pragma unroll 1
    for (int ch = 0; ch < NT; ch += 2) {
        b1 = *(const half8*)(bp + (size_t)(ch + 1) * 16 * DIM);
        t1 = tp[(ch + 1) * 16];
        {
            float wq = exp2v(t0 - l2eTmax);
            floatx4 acc[2];
            #pragma unroll
            for (int s = 0; s < 2; s++) acc[s] = (floatx4){0.f, 0.f, 0.f, 0.f};
            #pragma unroll
            for (int s = 0; s < 2; s++)
                acc[s] = __builtin_amdgcn_mfma_f32_16x16x32_f16(ah[s], b0, acc[s], 0, 0, 0);
            #pragma unroll
            for (int s = 0; s < 2; s++)
                #pragma unroll
                for (int r = 0; r < 4; r++)
                    sum[s][r] = fmaf(wq, exp2v(acc[s][r]), sum[s][r]);
        }
        if (ch + 2 < NT) {
            b0 = *(const half8*)(bp + (size_t)(ch + 2) * 16 * DIM);
            t0 = tp[(ch + 2) * 16];
        }
        {
            float wq = exp2v(t1 - l2eTmax);
            floatx4 acc[2];
            #pragma unroll
            for (int s = 0; s < 2; s++) acc[s] = (floatx4){0.f, 0.f, 0.f, 0.f};
            #pragma unroll
            for (int s = 0; s < 2; s++)
                acc[s] = __builtin_amdgcn_mfma_f32_16x16x32_f16(ah[s], b1, acc[s], 0, 0, 0);
            #pragma unroll
            for (int s = 0; s < 2; s++)
                #pragma unroll
                for (int r = 0; r < 4; r++)
                    sum[s][r] = fmaf(wq, exp2v(acc[s][r]), sum[s][r]);
        }
    }

    // reduce over 16 n-lanes, then across waves via LDS
    #pragma unroll
    for (int s = 0; s < 2; s++)
        #pragma unroll
        for (int r = 0; r < 4; r++) {
            float v = sum[s][r];
            #pragma unroll
            for (int m = 1; m < 16; m <<= 1) v += __shfl_xor(v, m, 64);
            if (n == 0) lsum[s * 16 + quad * 4 + r][w] = v;
        }
    __syncthreads();

    if (tid < RPB) {
        float T = (lsum[tid][0] + lsum[tid][1]) + (lsum[tid][2] + lsum[tid][3]);
        int l = row0 + tid;
        float lse = Tmax + __logf(T);
        float val = fa.qX[set][vbase + l] - lse;
        if (!fin) {
            val = 0.5f * (fa.pot[set][c][vbase + l] + val);
            fa.pot[set][c ^ 1][vbase + l] = val;
            float tc = val + fa.cwN[set][vbase + l];
            fa.tls[set][c ^ 1][vbase + l] = L2E * tc;
            float bmv = tc;
            #pragma unroll
            for (int m = 1; m < 16; m <<= 1) bmv = fmaxf(bmv, __shfl_xor(bmv, m, 64));
            if ((tid & 15) == 0)
                fa.bm[set][c ^ 1][batch * 128 + rb * 2 + (tid >> 4)] = bmv;
        } else {
            float partial = fa.sgn[set] * fa.wgt[set][vbase + l] * val;
            #pragma unroll
            for (int m = 1; m < 32; m <<= 1) partial += __shfl_xor(partial, m, 64);
            if (tid == 0) atomicAdd(fa.out, partial);
        }
    }
}

// Cooperative fused path: grid = 1024 blocks (<= half of the 8-blocks/CU
// capacity at launch_bounds(256,4) -> co-residency guaranteed with headroom).
// Each block handles TWO row-blocks sequentially per iteration.
__global__ __launch_bounds__(256, 4) void fused_kernel(FusedArgs fa) {
    cg::grid_group grid = cg::this_grid();
    __shared__ float lsum[RPB][4];
    const int bx = blockIdx.x;
    const int rbp   = bx & 31;          // row-pair within batch
    const int set   = (bx >> 5) & 3;
    const int batch = bx >> 7;

    int c = 0;
    #pragma unroll 1
    for (int it = 0; it <= 10; it++) {
        const bool fin = (it == 10);
        ct_pass(fa, set, batch, rbp * 2, fin, c, lsum);
        __syncthreads();   // lsum reuse between the two halves
        ct_pass(fa, set, batch, rbp * 2 + 1, fin, c, lsum);
        if (!fin) {
            grid.sync();
            c ^= 1;
        }
    }
}

// Fallback per-iteration path (no cooperative support / occupancy shortfall).
__global__ __launch_bounds__(256, 8) void iter_kernel(FusedArgs fa, int it, int c) {
    __shared__ float lsum[RPB][4];
    const int bx = blockIdx.x;
    const int rb    = bx & 63;
    const int set   = (bx >> 6) & 3;
    const int batch = bx >> 8;
    ct_pass(fa, set, batch, rb, it == 10, c, lsum);
}

struct InitArgs {
    const float *x, *a, *y, *b;
    float *c_x, *c_y, *qx, *qy;
    u16 *xh, *yh, *xsh, *ysh;
    float *f0, *g0, *fx0, *fy0;
    float *tlsF0, *tlsG0, *tlsFx0, *tlsFy0;
    float *bmF0, *bmG0, *bmFx0, *bmFy0;
    float *out;
};

__global__ __launch_bounds__(256) void init_kernel(InitArgs ia) {
    int idx = blockIdx.x * 256 + threadIdx.x;
    if (idx >= BN) return;
    if (idx == 0) ia.out[0] = 0.0f;
    const float* xp = ia.x + (size_t)idx * DIM;
    const float* yp = ia.y + (size_t)idx * DIM;
    u32* xhp  = (u32*)ia.xh  + (size_t)idx * (DIM / 2);
    u32* yhp  = (u32*)ia.yh  + (size_t)idx * (DIM / 2);
    u32* xshp = (u32*)ia.xsh + (size_t)idx * (DIM / 2);
    u32* yshp = (u32*)ia.ysh + (size_t)idx * (DIM / 2);
    float sx = 0.f, sy = 0.f;
    #pragma unroll
    for (int d = 0; d < DIM; d += 2) {
        float v0 = xp[d], v1 = xp[d + 1];
        sx += v0 * v0 + v1 * v1;
        xhp[d / 2]  = (u32)f2h_bits(v0) | ((u32)f2h_bits(v1) << 16);
        xshp[d / 2] = (u32)f2h_bits(L2E * v0) | ((u32)f2h_bits(L2E * v1) << 16);
        float u0 = yp[d], u1 = yp[d + 1];
        sy += u0 * u0 + u1 * u1;
        yhp[d / 2]  = (u32)f2h_bits(u0) | ((u32)f2h_bits(u1) << 16);
        yshp[d / 2] = (u32)f2h_bits(L2E * u0) | ((u32)f2h_bits(L2E * u1) << 16);
    }
    float qxv = 0.5f * sx, qyv = 0.5f * sy;
    ia.qx[idx] = qxv; ia.qy[idx] = qyv;
    float cxv = __logf(ia.a[idx]) - qxv;
    float cyv = __logf(ia.b[idx]) - qyv;
    ia.c_x[idx] = cxv; ia.c_y[idx] = cyv;
    ia.f0[idx] = 0.f; ia.g0[idx] = 0.f; ia.fx0[idx] = 0.f; ia.fy0[idx] = 0.f;
    ia.tlsF0[idx] = L2E * cxv; ia.tlsG0[idx] = L2E * cyv;
    ia.tlsFx0[idx] = L2E * cxv; ia.tlsFy0[idx] = L2E * cyv;
    // per-16-row blockmax of (0 + cw)
    float mx = cxv, my = cyv;
    #pragma unroll
    for (int m = 1; m < 16; m <<= 1) {
        mx = fmaxf(mx, __shfl_xor(mx, m, 32));
        my = fmaxf(my, __shfl_xor(my, m, 32));
    }
    if ((threadIdx.x & 15) == 0) {
        int g = idx >> 4;   // == batch*128 + 16-row group
        ia.bmF0[g] = mx; ia.bmFx0[g] = mx;
        ia.bmG0[g] = my; ia.bmFy0[g] = my;
    }
}

extern "C" void kernel_launch(void* const* d_in, const int* in_sizes, int n_in,
                              void* d_out, int out_size, void* d_ws, size_t ws_size,
                              hipStream_t stream) {
    const float* x = (const float*)d_in[0];
    const float* a = (const float*)d_in[1];
    const float* y = (const float*)d_in[2];
    const float* b = (const float*)d_in[3];
    float* out = (float*)d_out;

    float* ws = (float*)d_ws;
    float* c_x = ws + 0 * BN;
    float* c_y = ws + 1 * BN;
    float* qx  = ws + 2 * BN;
    float* qy  = ws + 3 * BN;
    float* fb[2]  = { ws + 4 * BN,  ws + 5 * BN };
    float* gb[2]  = { ws + 6 * BN,  ws + 7 * BN };
    float* fxb[2] = { ws + 8 * BN,  ws + 9 * BN };
    float* fyb[2] = { ws + 10 * BN, ws + 11 * BN };
    float* tlsF[2]  = { ws + 12 * BN, ws + 13 * BN };
    float* tlsG[2]  = { ws + 14 * BN, ws + 15 * BN };
    float* tlsFx[2] = { ws + 16 * BN, ws + 17 * BN };
    float* tlsFy[2] = { ws + 18 * BN, ws + 19 * BN };
    float* small = ws + 20 * BN;
    float* bmF[2]  = { small + 0 * 1024, small + 1 * 1024 };
    float* bmG[2]  = { small + 2 * 1024, small + 3 * 1024 };
    float* bmFx[2] = { small + 4 * 1024, small + 5 * 1024 };
    float* bmFy[2] = { small + 6 * 1024, small + 7 * 1024 };
    u16* bf = (u16*)(small + 8 * 1024);
    const size_t AS = (size_t)BN * DIM;
    u16* xh  = bf + 0 * AS;   // plain fp16 x
    u16* yh  = bf + 1 * AS;   // plain fp16 y
    u16* xsh = bf + 2 * AS;   // L2E-scaled fp16 x
    u16* ysh = bf + 3 * AS;   // L2E-scaled fp16 y

    InitArgs ia;
    ia.x = x; ia.a = a; ia.y = y; ia.b = b;
    ia.c_x = c_x; ia.c_y = c_y; ia.qx = qx; ia.qy = qy;
    ia.xh = xh; ia.yh = yh; ia.xsh = xsh; ia.ysh = ysh;
    ia.f0 = fb[0]; ia.g0 = gb[0]; ia.fx0 = fxb[0]; ia.fy0 = fyb[0];
    ia.tlsF0 = tlsF[0]; ia.tlsG0 = tlsG[0]; ia.tlsFx0 = tlsFx[0]; ia.tlsFy0 = tlsFy[0];
    ia.bmF0 = bmF[0]; ia.bmG0 = bmG[0]; ia.bmFx0 = bmFx[0]; ia.bmFy0 = bmFy[0];
    ia.out = out;
    init_kernel<<<BN / 256, 256, 0, stream>>>(ia);

    FusedArgs fa;
    // set0: fn = ct(g, log_b, kxy): rows X, cols Y, dot with a, sign +
    // set1: gn = ct(f, log_a, kyx): rows Y, cols X, dot with b, sign +
    // set2: sym x (kxx): dot with a, sign -      set3: sym y (kyy): dot with b, sign -
    fa.A[0] = xh;  fa.A[1] = yh;  fa.A[2] = xh;  fa.A[3] = yh;
    fa.Bp[0] = ysh; fa.Bp[1] = xsh; fa.Bp[2] = xsh; fa.Bp[3] = ysh;
    fa.qX[0] = qx; fa.qX[1] = qy; fa.qX[2] = qx; fa.qX[3] = qy;
    fa.wgt[0] = a; fa.wgt[1] = b; fa.wgt[2] = a; fa.wgt[3] = b;
    fa.sgn[0] = 1.0f / BATCH; fa.sgn[1] = 1.0f / BATCH;
    fa.sgn[2] = -1.0f / BATCH; fa.sgn[3] = -1.0f / BATCH;
    fa.cwN[0] = c_x; fa.cwN[1] = c_y; fa.cwN[2] = c_x; fa.cwN[3] = c_y;
    for (int p = 0; p < 2; p++) {
        fa.pot[0][p] = fb[p];  fa.pot[1][p] = gb[p];
        fa.pot[2][p] = fxb[p]; fa.pot[3][p] = fyb[p];
        fa.tls[0][p] = tlsF[p];  fa.tls[1][p] = tlsG[p];
        fa.tls[2][p] = tlsFx[p]; fa.tls[3][p] = tlsFy[p];
        fa.bm[0][p] = bmF[p];  fa.bm[1][p] = bmG[p];
        fa.bm[2][p] = bmFx[p]; fa.bm[3][p] = bmFy[p];
    }
    fa.out = out;

    // Deterministic path choice (capture-safe host query, same result every call):
    int maxBlocksPerCU = 0;
    hipError_t qerr = hipOccupancyMaxActiveBlocksPerMultiprocessor(
        &maxBlocksPerCU, (const void*)fused_kernel, 256, 0);
    bool use_coop = (qerr == hipSuccess) && ((long)maxBlocksPerCU * 256 >= 1024);

    if (use_coop) {
        void* kp[] = { &fa };
        hipLaunchCooperativeKernel((void*)fused_kernel, dim3(1024), dim3(256),
                                   kp, 0, stream);
    } else {
        int c = 0;
        for (int it = 0; it <= 10; it++) {
            iter_kernel<<<dim3(2048), 256, 0, stream>>>(fa, it, c);
            if (it < 10) c ^= 1;
        }
    }
}

// Round 14
// 342.289 us; speedup vs baseline: 1.0076x; 1.0076x over previous
//
#include <hip/hip_runtime.h>
#include <math.h>

#define BATCH 8
#define NPT   2048
#define DIM   32
#define RPB   32                      // rows per row-block: 2 strips of 16
#define CPW   (NPT / 4)               // 512 cols per wave
#define NT    (CPW / 16)              // 32 col-tiles of 16 per wave
#define L2E   1.44269504088896f
#define BN    (BATCH * NPT)

typedef __attribute__((ext_vector_type(8))) _Float16 half8;
typedef __attribute__((ext_vector_type(4))) float floatx4;
typedef unsigned short u16;
typedef unsigned int u32;

__device__ __forceinline__ u16 f2h_bits(float v) {
    _Float16 h = (_Float16)v;
    return *(u16*)&h;
}
__device__ __forceinline__ float exp2v(float x) { return __builtin_amdgcn_exp2f(x); }

// Streams: 0=F, 1=G, 2=Fx, 3=Fy. Set s reads pot-stream inS, writes stream s.
struct FusedArgs {
    const u16* A[4];       // row-side plain fp16 per set
    const u16* Bp[4];      // col-side log2e-scaled fp16 per set
    const float* qX[4];    // 0.5*||row||^2 per set
    const float* wgt[4];   // a or b per set (final dot weight)
    float sgn[4];          // +-1/BATCH
    float* pot[4][2];      // ping-pong potential buffers per stream
    float* tls[4][2];      // log2e*(pot+cw) per stream
    float* bm[4][2];       // [BATCH][128] per-16-row max of (pot+cw) per stream
    const float* cwN[4];   // cw to fold into tlsOut per set
    float* out;
};

// One damped-c-transform pass for one (set,batch,row-block).
// Factored no-rescale LSE: T = sum_k exp2(tv_k - L2E*Tmax) * exp2(log2e * x.y);
// lse = Tmax + ln(T). Dominant term >= 2^-92; wq >= 2^-101; T <= 2^103.
__global__ __launch_bounds__(256, 8) void iter_kernel(FusedArgs fa, int it, int c) {
    __shared__ float lsum[RPB][4];
    const int bx = blockIdx.x;
    const int rb    = bx & 63;
    const int set   = (bx >> 6) & 3;
    const int batch = bx >> 8;
    const bool fin  = (it == 10);

    const int tid = threadIdx.x;
    const int w = tid >> 6, lane = tid & 63, n = lane & 15, quad = lane >> 4;
    const int qk = quad * 8;
    const int row0 = rb * RPB;
    const size_t pbase = (size_t)batch * NPT * DIM;
    const size_t vbase = (size_t)batch * NPT;
    const int inS = (set == 0) ? 1 : (set == 1) ? 0 : set;

    const u16* __restrict__ Ah = fa.A[set] + pbase;
    const u16* __restrict__ Bh = fa.Bp[set] + pbase;
    const float* __restrict__ tlsIn = fa.tls[inS][c] + vbase;
    const float* __restrict__ bmIn  = fa.bm[inS][c];

    // A fragments for 2 row-strips: A[m=n][k=quad*8+j]
    half8 ah[2];
    #pragma unroll
    for (int s = 0; s < 2; s++) {
        size_t off = (size_t)(row0 + s * 16 + n) * DIM + qk;
        ah[s] = *(const half8*)(Ah + off);
    }

    // Tmax = max_k (pot_k + cw_k): wave-local reduce of 128 16-row maxes
    float tmv = fmaxf(bmIn[batch * 128 + lane], bmIn[batch * 128 + 64 + lane]);
    #pragma unroll
    for (int m = 1; m < 64; m <<= 1) tmv = fmaxf(tmv, __shfl_xor(tmv, m, 64));
    const float Tmax = tmv;
    const float l2eTmax = L2E * Tmax;

    float sum[2][4];
    #pragma unroll
    for (int s = 0; s < 2; s++)
        #pragma unroll
        for (int r = 0; r < 4; r++) sum[s][r] = 0.0f;

    const int c0 = w * CPW + n;                    // this lane's col in tile 0
    const u16* bp = Bh + (size_t)c0 * DIM + qk;    // advances 16*DIM per tile
    const float* tp = tlsIn + c0;

    half8 b0, b1;
    float t0, t1;
    b0 = *(const half8*)bp;  t0 = *tp;

    #pragma unroll 1
    for (int ch = 0; ch < NT; ch += 2) {
        b1 = *(const half8*)(bp + (size_t)(ch + 1) * 16 * DIM);
        t1 = tp[(ch + 1) * 16];
        {
            float wq = exp2v(t0 - l2eTmax);
            floatx4 acc[2];
            #pragma unroll
            for (int s = 0; s < 2; s++) acc[s] = (floatx4){0.f, 0.f, 0.f, 0.f};
            #pragma unroll
            for (int s = 0; s < 2; s++)
                acc[s] = __builtin_amdgcn_mfma_f32_16x16x32_f16(ah[s], b0, acc[s], 0, 0, 0);
            #pragma unroll
            for (int s = 0; s < 2; s++)
                #pragma unroll
                for (int r = 0; r < 4; r++)
                    sum[s][r] = fmaf(wq, exp2v(acc[s][r]), sum[s][r]);
        }
        if (ch + 2 < NT) {
            b0 = *(const half8*)(bp + (size_t)(ch + 2) * 16 * DIM);
            t0 = tp[(ch + 2) * 16];
        }
        {
            float wq = exp2v(t1 - l2eTmax);
            floatx4 acc[2];
            #pragma unroll
            for (int s = 0; s < 2; s++) acc[s] = (floatx4){0.f, 0.f, 0.f, 0.f};
            #pragma unroll
            for (int s = 0; s < 2; s++)
                acc[s] = __builtin_amdgcn_mfma_f32_16x16x32_f16(ah[s], b1, acc[s], 0, 0, 0);
            #pragma unroll
            for (int s = 0; s < 2; s++)
                #pragma unroll
                for (int r = 0; r < 4; r++)
                    sum[s][r] = fmaf(wq, exp2v(acc[s][r]), sum[s][r]);
        }
    }

    // reduce over 16 n-lanes, then across waves via LDS
    #pragma unroll
    for (int s = 0; s < 2; s++)
        #pragma unroll
        for (int r = 0; r < 4; r++) {
            float v = sum[s][r];
            #pragma unroll
            for (int m = 1; m < 16; m <<= 1) v += __shfl_xor(v, m, 64);
            if (n == 0) lsum[s * 16 + quad * 4 + r][w] = v;
        }
    __syncthreads();

    if (tid < RPB) {
        float T = (lsum[tid][0] + lsum[tid][1]) + (lsum[tid][2] + lsum[tid][3]);
        int l = row0 + tid;
        float lse = Tmax + __logf(T);
        float val = fa.qX[set][vbase + l] - lse;
        if (!fin) {
            val = 0.5f * (fa.pot[set][c][vbase + l] + val);
            fa.pot[set][c ^ 1][vbase + l] = val;
            float tc = val + fa.cwN[set][vbase + l];
            fa.tls[set][c ^ 1][vbase + l] = L2E * tc;
            float bmv = tc;
            #pragma unroll
            for (int m = 1; m < 16; m <<= 1) bmv = fmaxf(bmv, __shfl_xor(bmv, m, 64));
            if ((tid & 15) == 0)
                fa.bm[set][c ^ 1][batch * 128 + rb * 2 + (tid >> 4)] = bmv;
        } else {
            // final evaluation: fold the weighted dot directly into out[0]
            float partial = fa.sgn[set] * fa.wgt[set][vbase + l] * val;
            #pragma unroll
            for (int m = 1; m < 32; m <<= 1) partial += __shfl_xor(partial, m, 64);
            if (tid == 0) atomicAdd(fa.out, partial);
        }
    }
}

struct InitArgs {
    const float *x, *a, *y, *b;
    float *c_x, *c_y, *qx, *qy;
    u16 *xh, *yh, *xsh, *ysh;
    float *f0, *g0, *fx0, *fy0;
    float *tlsF0, *tlsG0, *tlsFx0, *tlsFy0;
    float *bmF0, *bmG0, *bmFx0, *bmFy0;
    float *out;
};

__global__ __launch_bounds__(256) void init_kernel(InitArgs ia) {
    int idx = blockIdx.x * 256 + threadIdx.x;
    if (idx >= BN) return;
    if (idx == 0) ia.out[0] = 0.0f;
    const float* xp = ia.x + (size_t)idx * DIM;
    const float* yp = ia.y + (size_t)idx * DIM;
    u32* xhp  = (u32*)ia.xh  + (size_t)idx * (DIM / 2);
    u32* yhp  = (u32*)ia.yh  + (size_t)idx * (DIM / 2);
    u32* xshp = (u32*)ia.xsh + (size_t)idx * (DIM / 2);
    u32* yshp = (u32*)ia.ysh + (size_t)idx * (DIM / 2);
    float sx = 0.f, sy = 0.f;
    #pragma unroll
    for (int d = 0; d < DIM; d += 2) {
        float v0 = xp[d], v1 = xp[d + 1];
        sx += v0 * v0 + v1 * v1;
        xhp[d / 2]  = (u32)f2h_bits(v0) | ((u32)f2h_bits(v1) << 16);
        xshp[d / 2] = (u32)f2h_bits(L2E * v0) | ((u32)f2h_bits(L2E * v1) << 16);
        float u0 = yp[d], u1 = yp[d + 1];
        sy += u0 * u0 + u1 * u1;
        yhp[d / 2]  = (u32)f2h_bits(u0) | ((u32)f2h_bits(u1) << 16);
        yshp[d / 2] = (u32)f2h_bits(L2E * u0) | ((u32)f2h_bits(L2E * u1) << 16);
    }
    float qxv = 0.5f * sx, qyv = 0.5f * sy;
    ia.qx[idx] = qxv; ia.qy[idx] = qyv;
    float cxv = __logf(ia.a[idx]) - qxv;
    float cyv = __logf(ia.b[idx]) - qyv;
    ia.c_x[idx] = cxv; ia.c_y[idx] = cyv;
    ia.f0[idx] = 0.f; ia.g0[idx] = 0.f; ia.fx0[idx] = 0.f; ia.fy0[idx] = 0.f;
    ia.tlsF0[idx] = L2E * cxv; ia.tlsG0[idx] = L2E * cyv;
    ia.tlsFx0[idx] = L2E * cxv; ia.tlsFy0[idx] = L2E * cyv;
    // per-16-row blockmax of (0 + cw)
    float mx = cxv, my = cyv;
    #pragma unroll
    for (int m = 1; m < 16; m <<= 1) {
        mx = fmaxf(mx, __shfl_xor(mx, m, 32));
        my = fmaxf(my, __shfl_xor(my, m, 32));
    }
    if ((threadIdx.x & 15) == 0) {
        int g = idx >> 4;   // == batch*128 + 16-row group
        ia.bmF0[g] = mx; ia.bmFx0[g] = mx;
        ia.bmG0[g] = my; ia.bmFy0[g] = my;
    }
}

extern "C" void kernel_launch(void* const* d_in, const int* in_sizes, int n_in,
                              void* d_out, int out_size, void* d_ws, size_t ws_size,
                              hipStream_t stream) {
    const float* x = (const float*)d_in[0];
    const float* a = (const float*)d_in[1];
    const float* y = (const float*)d_in[2];
    const float* b = (const float*)d_in[3];
    float* out = (float*)d_out;

    float* ws = (float*)d_ws;
    float* c_x = ws + 0 * BN;
    float* c_y = ws + 1 * BN;
    float* qx  = ws + 2 * BN;
    float* qy  = ws + 3 * BN;
    float* fb[2]  = { ws + 4 * BN,  ws + 5 * BN };
    float* gb[2]  = { ws + 6 * BN,  ws + 7 * BN };
    float* fxb[2] = { ws + 8 * BN,  ws + 9 * BN };
    float* fyb[2] = { ws + 10 * BN, ws + 11 * BN };
    float* tlsF[2]  = { ws + 12 * BN, ws + 13 * BN };
    float* tlsG[2]  = { ws + 14 * BN, ws + 15 * BN };
    float* tlsFx[2] = { ws + 16 * BN, ws + 17 * BN };
    float* tlsFy[2] = { ws + 18 * BN, ws + 19 * BN };
    float* small = ws + 20 * BN;
    float* bmF[2]  = { small + 0 * 1024, small + 1 * 1024 };
    float* bmG[2]  = { small + 2 * 1024, small + 3 * 1024 };
    float* bmFx[2] = { small + 4 * 1024, small + 5 * 1024 };
    float* bmFy[2] = { small + 6 * 1024, small + 7 * 1024 };
    u16* bf = (u16*)(small + 8 * 1024);
    const size_t AS = (size_t)BN * DIM;
    u16* xh  = bf + 0 * AS;   // plain fp16 x
    u16* yh  = bf + 1 * AS;   // plain fp16 y
    u16* xsh = bf + 2 * AS;   // L2E-scaled fp16 x
    u16* ysh = bf + 3 * AS;   // L2E-scaled fp16 y

    InitArgs ia;
    ia.x = x; ia.a = a; ia.y = y; ia.b = b;
    ia.c_x = c_x; ia.c_y = c_y; ia.qx = qx; ia.qy = qy;
    ia.xh = xh; ia.yh = yh; ia.xsh = xsh; ia.ysh = ysh;
    ia.f0 = fb[0]; ia.g0 = gb[0]; ia.fx0 = fxb[0]; ia.fy0 = fyb[0];
    ia.tlsF0 = tlsF[0]; ia.tlsG0 = tlsG[0]; ia.tlsFx0 = tlsFx[0]; ia.tlsFy0 = tlsFy[0];
    ia.bmF0 = bmF[0]; ia.bmG0 = bmG[0]; ia.bmFx0 = bmFx[0]; ia.bmFy0 = bmFy[0];
    ia.out = out;
    init_kernel<<<BN / 256, 256, 0, stream>>>(ia);

    FusedArgs fa;
    // set0: fn = ct(g, log_b, kxy): rows X, cols Y, dot with a, sign +
    // set1: gn = ct(f, log_a, kyx): rows Y, cols X, dot with b, sign +
    // set2: sym x (kxx): dot with a, sign -      set3: sym y (kyy): dot with b, sign -
    fa.A[0] = xh;  fa.A[1] = yh;  fa.A[2] = xh;  fa.A[3] = yh;
    fa.Bp[0] = ysh; fa.Bp[1] = xsh; fa.Bp[2] = xsh; fa.Bp[3] = ysh;
    fa.qX[0] = qx; fa.qX[1] = qy; fa.qX[2] = qx; fa.qX[3] = qy;
    fa.wgt[0] = a; fa.wgt[1] = b; fa.wgt[2] = a; fa.wgt[3] = b;
    fa.sgn[0] = 1.0f / BATCH; fa.sgn[1] = 1.0f / BATCH;
    fa.sgn[2] = -1.0f / BATCH; fa.sgn[3] = -1.0f / BATCH;
    fa.cwN[0] = c_x; fa.cwN[1] = c_y; fa.cwN[2] = c_x; fa.cwN[3] = c_y;
    for (int p = 0; p < 2; p++) {
        fa.pot[0][p] = fb[p];  fa.pot[1][p] = gb[p];
        fa.pot[2][p] = fxb[p]; fa.pot[3][p] = fyb[p];
        fa.tls[0][p] = tlsF[p];  fa.tls[1][p] = tlsG[p];
        fa.tls[2][p] = tlsFx[p]; fa.tls[3][p] = tlsFy[p];
        fa.bm[0][p] = bmF[p];  fa.bm[1][p] = bmG[p];
        fa.bm[2][p] = bmFx[p]; fa.bm[3][p] = bmFy[p];
    }
    fa.out = out;

    int c = 0;
    for (int it = 0; it <= 10; it++) {
        iter_kernel<<<dim3(2048), 256, 0, stream>>>(fa, it, c);
        if (it < 10) c ^= 1;
    }
}